// Round 14
// baseline (893.417 us; speedup 1.0000x reference)
//
#include <hip/hip_runtime.h>
#include <stdint.h>
#include <math.h>

typedef unsigned long long u64;
typedef unsigned int u32;
typedef float float4a __attribute__((ext_vector_type(4), aligned(4)));
typedef unsigned long long u64x2 __attribute__((ext_vector_type(2), aligned(16)));

// ---------------- workspace layout (bytes) ----------------
static const size_t OFF_CTL   = 0;          // [0]=u64 pfx, [8]=u32 tgt, [12]=u32 count, [16]=u32 done
static const size_t OFF_HIST  = 1024;       // 4 passes * 256 * 4 = 4 KB (8KB zeroed)
static const size_t OFF_WCV   = 4588544;    // 589824*4  [tap][ic][oc]
static const size_t OFF_XD    = 6947840;    // 16384*256*4 (conv out f32, HWC)
static const size_t OFF_BOX   = 23725056;   // 147456*16 (float4)
static const size_t OFF_KEYS  = 26084352;   // 147456*8
static const size_t OFF_CKEY  = 27264000;   // 6144*8
static const size_t OFF_CIDX  = 27313152;   // 6144*4
static const size_t OFF_TB    = 27337728;   // 6000*16
static const size_t OFF_ALIVE = 27458048;   // 128*8
static const size_t OFF_FPAD  = 32067584;   // 256*130*132*4 = 17571840  end ~49.6 MB
// paired NMS mask ALIASES featP (featP is dead after conv3x3; nms_mask fully
// rewrites its slots every launch -> replay-deterministic): 6000*128*8 = 6.14MB
static const size_t OFF_MASKP = OFF_FPAD;

// XLA-CPU / Eigen / Cephes f32 exp (FMA form) — bit-matches the np reference.
__device__ __forceinline__ float exp_xla(float x) {
    float m = floorf(__fmaf_rn(x, 1.44269504088896341f, 0.5f));
    float r = __fmaf_rn(m, -0.693359375f, x);
    r = __fmaf_rn(m, 2.12194440e-4f, r);
    float r2 = r * r;
    float p = 1.9875691500e-4f;
    p = __fmaf_rn(p, r, 1.3981999507e-3f);
    p = __fmaf_rn(p, r, 8.3334519073e-3f);
    p = __fmaf_rn(p, r, 4.1665795894e-2f);
    p = __fmaf_rn(p, r, 1.6666665459e-1f);
    p = __fmaf_rn(p, r, 5.0000001201e-1f);
    p = __fmaf_rn(p, r2, r);
    p = __fadd_rn(p, 1.0f);
    int mi = (int)m;
    return p * __int_as_float((mi + 127) << 23);
}

// async global->LDS, 16B per lane, wave-uniform LDS base + lane*16
__device__ __forceinline__ void gload_lds16(const void* g, void* l) {
    __builtin_amdgcn_global_load_lds(
        (const __attribute__((address_space(1))) void*)g,
        (__attribute__((address_space(3))) void*)l, 16, 0, 0);
}

// ---------------- prep (FUSED): wcv transpose + feature pad ------------------
__global__ void prep_all(const float* __restrict__ rpn_w, float* __restrict__ wcv,
                         const float* __restrict__ feat, float* __restrict__ featP) {
    int b = blockIdx.x;
    if (b < 2304) {
        int t = b * 256 + threadIdx.x;
        if (t >= 589824) return;
        int tap = t / 65536, rem = t % 65536, ic = rem / 256, oc = rem % 256;
        wcv[t] = rpn_w[oc * 2304 + ic * 9 + tap];
    } else {
        int t = (b - 2304) * 256 + threadIdx.x;
        if (t >= 256 * 130 * 132) return;
        int ic = t / 17160, rem = t % 17160, y = rem / 132, x = rem % 132;
        int sy = y - 1, sx = x - 1;
        float v = 0.f;
        if (sy >= 0 && sy < 128 && sx >= 0 && sx < 128)
            v = feat[ic * 16384 + sy * 128 + sx];
        featP[t] = v;
    }
}

// ---------------- conv3x3 v7: 512-thread blocks, 4 waves/SIMD ----------------
// R12 analysis: v4's 42% idle = ~250cy L2 feature latency vs 128cy FMA with
// only 2 waves/SIMD to hide it. R2's occupancy attempt failed because it
// SHRANK per-thread work; v7 keeps the per-thread tiling BYTE-IDENTICAL
// (4px x 8oc, 1 global dwordx4 + 2 LDS broadcast b128 + 32 FMA per ic) and
// merges two v4 blocks into one 512-thread block (oc-block 64, sW 64KB):
// 256 blocks, 2 blocks/CU, 16 waves/CU = 4 waves/SIMD. Per-CU vmem/LDS
// demand unchanged; latency-hiding pool doubled. Per-output chain
// (tap-major, ic 0..255 ascending, one f32 acc, __fmaf_rn) -> bit-exact.
__global__ __launch_bounds__(512, 4) void conv3x3(const float* __restrict__ featP,
                                                  const float* __restrict__ wcv,
                                                  const float* __restrict__ rpn_b,
                                                  float* __restrict__ xd) {
    __shared__ float sW[16384];                // [ic][64 oc] for current tap
    const int band = blockIdx.x & 7;           // tile row (XCD-pinned)
    const int slot = blockIdx.x >> 3;          // 0..31
    const int tx = slot & 7, ocb = slot >> 3;  // tile col, oc-block(64)
    const int oc0 = ocb * 64;
    const int tid = threadIdx.x;
    const int wid = tid >> 6;                  // wave 0..7 -> 8 oc each
    const int lane = tid & 63;
    const int py = lane >> 2, px0 = (lane & 3) * 4;   // wave covers 16x16 px
    const int gy = band * 16 + py, gx0 = tx * 16 + px0;
    const int ocB = oc0 + wid * 8;
    float acc[4][8];
#pragma unroll
    for (int p = 0; p < 4; ++p)
#pragma unroll
        for (int o = 0; o < 8; ++o) acc[p][o] = 0.f;
#pragma unroll
    for (int tap = 0; tap < 9; ++tap) {        // k-major: tap (ky,kx)
        __syncthreads();
        for (int idx = tid; idx < 16384; idx += 512)
            sW[idx] = wcv[tap * 65536 + (idx >> 6) * 256 + oc0 + (idx & 63)];
        __syncthreads();
        const float* fp = featP + (size_t)(gy + tap / 3) * 132 + (gx0 + tap % 3);
        const float* wl = sW + wid * 8;        // wave-uniform -> LDS broadcast
#pragma unroll 4
        for (int ic = 0; ic < 256; ++ic) {     // k-minor: ic ascending
            float4a fA = *(const float4a*)(fp + (size_t)ic * 17160);
            float4a w0 = *(const float4a*)(wl + ic * 64);
            float4a w1 = *(const float4a*)(wl + ic * 64 + 4);
#pragma unroll
            for (int p = 0; p < 4; ++p) {
#pragma unroll
                for (int o = 0; o < 4; ++o)
                    acc[p][o] = __fmaf_rn(fA[p], w0[o], acc[p][o]);
#pragma unroll
                for (int o = 0; o < 4; ++o)
                    acc[p][4 + o] = __fmaf_rn(fA[p], w1[o], acc[p][4 + o]);
            }
        }
    }
#pragma unroll
    for (int p = 0; p < 4; ++p) {
        float* op = xd + (size_t)(gy * 128 + gx0 + p) * 256 + ocB;
#pragma unroll
        for (int o = 0; o < 8; ++o) {
            float v = __fadd_rn(acc[p][o], rpn_b[ocB + o]);
            op[o] = v > 0.f ? v : 0.f;
        }
    }
}

// ---------------- heads+decode FUSED: 1x1 convs -> softmax -> boxes/keys -----
__global__ __launch_bounds__(256, 1) void heads_decode(const float* __restrict__ xd,
                                                       const float* __restrict__ cls_w,
                                                       const float* __restrict__ box_w,
                                                       const float* __restrict__ cls_b,
                                                       const float* __restrict__ box_b,
                                                       float4* __restrict__ boxes,
                                                       u64* __restrict__ keys) {
    __shared__ float sX[4][260];
    __shared__ float sD[4][54];
    const int tid = threadIdx.x;
    const int pix0 = blockIdx.x * 4;
    for (int idx = tid; idx < 1024; idx += 256)
        sX[idx >> 8][idx & 255] = xd[(size_t)(pix0 + (idx >> 8)) * 256 + (idx & 255)];
    __syncthreads();
    if (tid < 216) {
        const int pl = tid / 54, o = tid % 54;
        const float* wr = (o < 18) ? (cls_w + o * 256) : (box_w + (o - 18) * 256);
        const float4* x4 = (const float4*)&sX[pl][0];
        const float4* w4 = (const float4*)wr;
        float acc = 0.f;
        for (int q = 0; q < 64; ++q) {
            float4 xv = x4[q];
            float4 wv = w4[q];
            acc = __fmaf_rn(xv.x, wv.x, acc);
            acc = __fmaf_rn(xv.y, wv.y, acc);
            acc = __fmaf_rn(xv.z, wv.z, acc);
            acc = __fmaf_rn(xv.w, wv.w, acc);
        }
        sD[pl][o] = acc;
    }
    __syncthreads();
    if (tid >= 36) return;
    const int pl = tid / 9, a = tid % 9;
    const int pix = pix0 + pl;
    const float* dt = sD[pl];
    float d[54];
#pragma unroll
    for (int i = 0; i < 54; ++i)
        d[i] = __fadd_rn(dt[i], (i < 18 ? cls_b[i] : box_b[i - 18]));
    float m = d[0];
#pragma unroll
    for (int i = 1; i < 18; ++i) m = fmaxf(m, d[i]);
    float e[18];
#pragma unroll
    for (int i = 0; i < 18; ++i) e[i] = exp_xla(__fsub_rn(d[i], m));
    float s = e[0];
#pragma unroll
    for (int i = 1; i < 18; ++i) s = __fadd_rn(s, e[i]);
    const int y = pix >> 7, x = pix & 127;
    const float shx = (float)(x * 32), shy = (float)(y * 32);
    const float AW[9] = {368.f, 736.f, 1472.f, 256.f, 512.f, 1024.f, 176.f, 352.f, 704.f};
    const float AH[9] = {192.f, 384.f, 768.f, 256.f, 512.f, 1024.f, 352.f, 704.f, 1408.f};
    float score = e[9 + a] / s;
    float wa = AW[a], ha = AH[a];
    float cxa = __fadd_rn(shx, 7.5f), cya = __fadd_rn(shy, 7.5f);
    float dx = d[18 + 4 * a], dyy = d[19 + 4 * a];
    float dw = d[20 + 4 * a], dh = d[21 + 4 * a];
    float cx = __fadd_rn(__fmul_rn(dx, wa), cxa);
    float cy = __fadd_rn(__fmul_rn(dyy, ha), cya);
    float pw = __fmul_rn(wa, exp_xla(dw));
    float ph = __fmul_rn(ha, exp_xla(dh));
    float hx = __fmul_rn(0.5f, pw), hy = __fmul_rn(0.5f, ph);
    float x1 = fminf(fmaxf(__fsub_rn(cx, hx), 0.f), 4095.f);
    float y1 = fminf(fmaxf(__fsub_rn(cy, hy), 0.f), 4095.f);
    float x2 = fminf(fmaxf(__fadd_rn(cx, hx), 0.f), 4095.f);
    float y2 = fminf(fmaxf(__fadd_rn(cy, hy), 0.f), 4095.f);
    float vw = __fadd_rn(__fsub_rn(x2, x1), 1.0f);
    float vh = __fadd_rn(__fsub_rn(y2, y1), 1.0f);
    bool valid = (vw >= 16.0f) && (vh >= 16.0f);
    int i = pix * 9 + a;
    boxes[i] = make_float4(x1, y1, x2, y2);
    u64 k;
    if (valid) {
        u32 b = __float_as_uint(score);
        k = ((u64)(u32)~(b | 0x80000000u) << 32) | (u32)i;
    } else {
        k = (0xFFFFFFFFULL << 32) | (u32)i;
    }
    keys[i] = k;
}

// ---------------- radix select + compact, SINGLE KERNEL ----------------------
// 4 passes of 8 bits over the score word, then inline compact. Inter-block
// sync per pass: device atomics + threadfence + done-counter spin (64 blocks
// on 256 CUs always co-resident). Every block redundantly scans the
// (atomic-RMW-read, XCD-coherent) histogram -> no cross-pass globals.
__global__ __launch_bounds__(256) void radix_compact(const u64* __restrict__ keys,
                                                     u32* __restrict__ ghist,
                                                     u32* done, u32* count,
                                                     u64* __restrict__ ckey,
                                                     u32* __restrict__ cidx,
                                                     u64* __restrict__ alive0) {
    __shared__ u32 lh[256];
    __shared__ u32 sh[256];
    __shared__ u32 incl[256];
    __shared__ u32 bdig, btgt;
    const int t = threadIdx.x;
    if (blockIdx.x == 0 && t < 128) alive0[t] = 0ULL;   // consumed next kernel
    u64 pref = 0;        // uniform across blocks (identical redundant scans)
    u32 target = 6000;
    for (int pass = 0; pass < 4; ++pass) {
        lh[t] = 0;
        __syncthreads();
        const int shift = 56 - 8 * pass;
        for (int i = blockIdx.x * 256 + t; i < 147456; i += 64 * 256) {
            u64 k = keys[i];
            bool match = (pass == 0) || ((k >> (shift + 8)) == pref);
            if (match) atomicAdd(&lh[(u32)(k >> shift) & 0xFFu], 1u);
        }
        __syncthreads();
        if (lh[t]) atomicAdd(&ghist[pass * 256 + t], lh[t]);
        __threadfence();                   // hist visible before done++
        __syncthreads();
        if (t == 0) {
            atomicAdd(done, 1u);
            const u32 need = 64u * (u32)(pass + 1);
            while (atomicAdd(done, 0u) < need) { }   // spin: all 64 co-resident
        }
        __syncthreads();
        u32 hv = atomicAdd(&ghist[pass * 256 + t], 0u);  // coherent RMW read
        sh[t] = hv;
        incl[t] = hv;
        __syncthreads();
        for (int off = 1; off < 256; off <<= 1) {
            u32 v = (t >= off) ? incl[t - off] : 0u;
            __syncthreads();
            incl[t] += v;
            __syncthreads();
        }
        u32 before = incl[t] - sh[t];
        if (before < target && target <= incl[t]) { bdig = (u32)t; btgt = target - before; }
        __syncthreads();
        pref = (pref << 8) | (u64)bdig;
        target = btgt;
    }
    // pref = exact 32-bit score boundary; compact inline (order-independent:
    // rank_scatter ranks by key value). Slack: 6000 + score-word ties <= 6144.
    for (int i = blockIdx.x * 256 + t; i < 147456; i += 64 * 256) {
        u64 k = keys[i];
        if ((k >> 32) <= pref) {
            u32 pos = atomicAdd(count, 1u);
            if (pos < 6144) { ckey[pos] = k; cidx[pos] = (u32)(k & 0xFFFFFFFFu); }
        }
    }
}

// ---------------- exact rank + gather + FUSED alive bitmask ------------------
__global__ __launch_bounds__(256) void rank_scatter(const u64* __restrict__ ckey,
                                                    const u32* __restrict__ cidx,
                                                    const u32* __restrict__ count,
                                                    const float4* __restrict__ boxes,
                                                    float4* __restrict__ tb,
                                                    u64* __restrict__ alive0) {
    __shared__ u64 LK[6144];
    int N = (int)*count; if (N > 6144) N = 6144;
    for (int i = threadIdx.x; i < N; i += 256) LK[i] = ckey[i];
    __syncthreads();
    int e = blockIdx.x * 256 + threadIdx.x;
    if (e >= N) return;
    u64 myK = LK[e];
    u32 myI = cidx[e];
    int rank = 0;
    for (int c = 0; c < N; ++c) rank += (LK[c] < myK);
    if (rank < 6000) {
        tb[rank] = boxes[myI];
        atomicOr(&alive0[rank >> 6], 1ULL << (rank & 63));
    }
}

// ---------------- suppression bitmask, PAIRED layout -------------------------
// Row j = 128 u64; word w at slot 2*(w&63)+(w>>6): lane l's pair (l, 64+l)
// is 16B contiguous -> nms_seq reads it with ONE ds_read_b128; row = 1024B =
// one gload_lds16 sweep.
__global__ __launch_bounds__(256) void nms_mask(const float4* __restrict__ tb,
                                                u64* __restrict__ mask) {
    int tid = blockIdx.x * 256 + threadIdx.x;
    if (tid >= 6000 * 94) return;
    int j = tid / 94, w = tid % 94;
    float4 bj = tb[j];
    float arJ = __fmul_rn(__fadd_rn(__fsub_rn(bj.z, bj.x), 1.0f),
                          __fadd_rn(__fsub_rn(bj.w, bj.y), 1.0f));
    u64 m = 0;
    int base = w * 64;
#pragma unroll 4
    for (int b = 0; b < 64; ++b) {
        int i = base + b;
        if (i >= 6000) break;
        float4 bi = tb[i];
        float arI = __fmul_rn(__fadd_rn(__fsub_rn(bi.z, bi.x), 1.0f),
                              __fadd_rn(__fsub_rn(bi.w, bi.y), 1.0f));
        float xx1 = fmaxf(bj.x, bi.x), yy1 = fmaxf(bj.y, bi.y);
        float xx2 = fminf(bj.z, bi.z), yy2 = fminf(bj.w, bi.w);
        float ww = fmaxf(__fadd_rn(__fsub_rn(xx2, xx1), 1.0f), 0.0f);
        float hh = fmaxf(__fadd_rn(__fsub_rn(yy2, yy1), 1.0f), 0.0f);
        float inter = __fmul_rn(ww, hh);
        float uni = __fsub_rn(__fadd_rn(arJ, arI), inter);
        float iou = inter / uni;
        if (iou > 0.7f) m |= (1ULL << b);
    }
    mask[(size_t)j * 128 + 2 * (w & 63) + (w >> 6)] = m;
}

// ---------------- sequential NMS v4: paired rows, dbuf prefetched window -----
__global__ __launch_bounds__(64, 1) void nms_seq(const u64* __restrict__ alive0,
                                                 const u64* __restrict__ mask,
                                                 const float4* __restrict__ tb,
                                                 float* __restrict__ out) {
    __shared__ __align__(16) u64 lwin[2][64 * 128];   // 2 x 64KB windows
    __shared__ u32 sel[1000];
    const int lane = threadIdx.x;
    u64 wl = alive0[lane];
    u64 wh = (lane < 30) ? alive0[64 + lane] : 0ULL;
    int base = -1000000;   // force refill on first selection
    int pbase = -1;        // prefetch window start (-1 = none), in buf[cur^1]
    int cur = 0;
    int k = 0;
    for (; k < 1000; ++k) {
        // ---- j = first alive (strictly increasing across iterations) ----
        int j;
        {
            u64 blo = __ballot(wl != 0ULL);
            if (blo) {
                int l = __ffsll((long long)blo) - 1;
                u32 a = __builtin_amdgcn_readlane((u32)wl, l);
                u32 b = __builtin_amdgcn_readlane((u32)(wl >> 32), l);
                u64 w = ((u64)b << 32) | (u64)a;
                j = l * 64 + __ffsll((long long)w) - 1;
            } else {
                u64 bhi = __ballot(wh != 0ULL);
                if (!bhi) break;  // exhausted: remaining out rows stay 0
                int l = __ffsll((long long)bhi) - 1;
                u32 a = __builtin_amdgcn_readlane((u32)wh, l);
                u32 b = __builtin_amdgcn_readlane((u32)(wh >> 32), l);
                u64 w = ((u64)b << 32) | (u64)a;
                j = (64 + l) * 64 + __ffsll((long long)w) - 1;
            }
        }
        if (lane == 0) sel[k] = (u32)j;
        // ---- window management (wave-uniform branch) ----
        if (j >= base + 64) {
            if (pbase >= 0 && j < pbase + 64) {
                // prefetched buffer covers j: just retire outstanding loads
                asm volatile("s_waitcnt vmcnt(0)" ::: "memory");
                cur ^= 1;
                base = pbase;
            } else {
                // jump past prefetch (or first iter): full refill into cur
                int js = (j > 5936) ? 5936 : j;     // clamp: stay inside mask
                asm volatile("s_waitcnt vmcnt(0)" ::: "memory");
                const char* gsrc = (const char*)mask + (size_t)js * 1024 + (size_t)lane * 16;
                char* ldst = (char*)&lwin[cur][0];
#pragma unroll
                for (int i = 0; i < 64; ++i)
                    gload_lds16(gsrc + (size_t)i * 1024, ldst + i * 1024);
                base = js;
                asm volatile("s_waitcnt vmcnt(0)" ::: "memory");
            }
            pbase = -1;
            if (base + 64 < 6000) {
                // issue prefetch of next window into the other buffer (NO wait)
                int ps = (base + 64 > 5936) ? 5936 : (base + 64);  // clamp
                const char* gs2 = (const char*)mask + (size_t)ps * 1024 + (size_t)lane * 16;
                char* ld2 = (char*)&lwin[cur ^ 1][0];
#pragma unroll
                for (int i = 0; i < 64; ++i)
                    gload_lds16(gs2 + (size_t)i * 1024, ld2 + i * 1024);
                pbase = ps;
            }
        }
        const int s = j - base;
        u64x2 rd = *(const u64x2*)&lwin[cur][(size_t)s * 128 + 2 * lane];
        u64 rl = rd.x;
        u64 rh = rd.y;
        // ---- apply row j (kills j itself via iou==1) ----
        wl &= ~rl;
        if (lane < 30) wh &= ~rh;
    }
    // ---- bulk gather: rois[k] = (0, tb[sel[k]]) — off the serial path ----
    __syncthreads();
    for (int r = lane; r < k; r += 64) {
        int j = (int)sel[r];
        float4 bj = tb[j];
        out[r * 5 + 1] = bj.x;
        out[r * 5 + 2] = bj.y;
        out[r * 5 + 3] = bj.z;
        out[r * 5 + 4] = bj.w;
    }
}

// ---------------- host ----------------
extern "C" void kernel_launch(void* const* d_in, const int* in_sizes, int n_in,
                              void* d_out, int out_size, void* d_ws, size_t ws_size,
                              hipStream_t stream) {
    const float *feat = nullptr, *rpn_w = nullptr, *rpn_b = nullptr;
    const float *cls_w = nullptr, *cls_b = nullptr, *box_w = nullptr, *box_b = nullptr;
    for (int i = 0; i < n_in; ++i) {
        switch (in_sizes[i]) {
            case 4194304: feat  = (const float*)d_in[i]; break;
            case 589824:  rpn_w = (const float*)d_in[i]; break;
            case 256:     rpn_b = (const float*)d_in[i]; break;
            case 4608:    cls_w = (const float*)d_in[i]; break;
            case 18:      cls_b = (const float*)d_in[i]; break;
            case 9216:    box_w = (const float*)d_in[i]; break;
            case 36:      box_b = (const float*)d_in[i]; break;
            default: break;  // image dims hardcoded (4096)
        }
    }

    char* w = (char*)d_ws;
    u32* ctlCount  = (u32*)(w + OFF_CTL + 12);
    u32* done      = (u32*)(w + OFF_CTL + 16);
    u32* hist      = (u32*)(w + OFF_HIST);
    float* wcv     = (float*)(w + OFF_WCV);
    float* xd      = (float*)(w + OFF_XD);
    float4* boxes  = (float4*)(w + OFF_BOX);
    u64* keys      = (u64*)(w + OFF_KEYS);
    u64* ckey      = (u64*)(w + OFF_CKEY);
    u32* cidx      = (u32*)(w + OFF_CIDX);
    float4* tb     = (float4*)(w + OFF_TB);
    u64* alive0    = (u64*)(w + OFF_ALIVE);
    u64* maskP     = (u64*)(w + OFF_MASKP);      // aliases featP (dead by then)
    float* featP   = (float*)(w + OFF_FPAD);

    hipMemsetAsync(d_ws, 0, OFF_HIST + 8 * 256 * 4, stream);  // ctl + done + hists
    hipMemsetAsync(d_out, 0, (size_t)out_size * sizeof(float), stream);

    prep_all<<<2304 + 17160, 256, 0, stream>>>(rpn_w, wcv, feat, featP);
    conv3x3<<<256, 512, 0, stream>>>(featP, wcv, rpn_b, xd);
    heads_decode<<<4096, 256, 0, stream>>>(xd, cls_w, box_w, cls_b, box_b, boxes, keys);
    radix_compact<<<64, 256, 0, stream>>>(keys, hist, done, ctlCount, ckey, cidx, alive0);
    rank_scatter<<<24, 256, 0, stream>>>(ckey, cidx, ctlCount, boxes, tb, alive0);
    nms_mask<<<2204, 256, 0, stream>>>(tb, maskP);
    nms_seq<<<1, 64, 0, stream>>>(alive0, maskP, tb, (float*)d_out);
}

// Round 16
// 877.375 us; speedup vs baseline: 1.0183x; 1.0183x over previous
//
#include <hip/hip_runtime.h>
#include <stdint.h>
#include <math.h>

typedef unsigned long long u64;
typedef unsigned int u32;
typedef float float4a __attribute__((ext_vector_type(4), aligned(4)));
typedef unsigned long long u64x2 __attribute__((ext_vector_type(2), aligned(16)));

// ---------------- workspace layout (bytes) ----------------
static const size_t OFF_CTL   = 0;          // [12]=u32 count, [16]=u32 done
static const size_t OFF_HIST  = 1024;       // 4 passes * 256 * 4 (8KB zeroed)
static const size_t OFF_WCV   = 4588544;    // 589824*4  [tap][ic][oc]
static const size_t OFF_XD    = 6947840;    // 16384*256*4 (conv out f32, HWC)
static const size_t OFF_BOX   = 23725056;   // 147456*16 (float4)
static const size_t OFF_KEYS  = 26084352;   // 147456*8
static const size_t OFF_CKEY  = 27264000;   // 6144*8
static const size_t OFF_CIDX  = 27313152;   // 6144*4
static const size_t OFF_TB    = 27337728;   // 6000*16
static const size_t OFF_ALIVE = 27458048;   // 128*8
static const size_t OFF_FPAD  = 32067584;   // 256*130*132*4 = 17571840  end ~49.6 MB
// paired NMS mask ALIASES featP (featP dead after conv3x3; nms_mask fully
// rewrites its slots every launch -> replay-deterministic): 6000*128*8 = 6.14MB
static const size_t OFF_MASKP = OFF_FPAD;

// XLA-CPU / Eigen / Cephes f32 exp (FMA form) — bit-matches the np reference.
__device__ __forceinline__ float exp_xla(float x) {
    float m = floorf(__fmaf_rn(x, 1.44269504088896341f, 0.5f));
    float r = __fmaf_rn(m, -0.693359375f, x);
    r = __fmaf_rn(m, 2.12194440e-4f, r);
    float r2 = r * r;
    float p = 1.9875691500e-4f;
    p = __fmaf_rn(p, r, 1.3981999507e-3f);
    p = __fmaf_rn(p, r, 8.3334519073e-3f);
    p = __fmaf_rn(p, r, 4.1665795894e-2f);
    p = __fmaf_rn(p, r, 1.6666665459e-1f);
    p = __fmaf_rn(p, r, 5.0000001201e-1f);
    p = __fmaf_rn(p, r2, r);
    p = __fadd_rn(p, 1.0f);
    int mi = (int)m;
    return p * __int_as_float((mi + 127) << 23);
}

// async global->LDS, 16B per lane, wave-uniform LDS base + lane*16
__device__ __forceinline__ void gload_lds16(const void* g, void* l) {
    __builtin_amdgcn_global_load_lds(
        (const __attribute__((address_space(1))) void*)g,
        (__attribute__((address_space(3))) void*)l, 16, 0, 0);
}

// ---------------- prep (FUSED): wcv transpose + feature pad ------------------
__global__ void prep_all(const float* __restrict__ rpn_w, float* __restrict__ wcv,
                         const float* __restrict__ feat, float* __restrict__ featP) {
    int b = blockIdx.x;
    if (b < 2304) {
        int t = b * 256 + threadIdx.x;
        if (t >= 589824) return;
        int tap = t / 65536, rem = t % 65536, ic = rem / 256, oc = rem % 256;
        wcv[t] = rpn_w[oc * 2304 + ic * 9 + tap];
    } else {
        int t = (b - 2304) * 256 + threadIdx.x;
        if (t >= 256 * 130 * 132) return;
        int ic = t / 17160, rem = t % 17160, y = rem / 132, x = rem % 132;
        int sy = y - 1, sx = x - 1;
        float v = 0.f;
        if (sy >= 0 && sy < 128 && sx >= 0 && sx < 128)
            v = feat[ic * 16384 + sy * 128 + sx];
        featP[t] = v;
    }
}

// ---------------- conv3x3 v4 (PROVEN, R4/R7/R10/R12: ~310us) -----------------
// 4px x 8oc/thread, 512 blocks x 256 threads (2 blocks/CU). Pipe balance:
// FMA 295k / vmem 295k / LDS 442k cy per CU — the structural optimum of this
// family (v2/v3/v5/v6/v7 all lost). LDS-broadcast weights (replay-safe;
// scalar K$ diverges — R6). Per-output chain (tap-major, ic 0..255
// ascending, one f32 acc, __fmaf_rn) -> bit-exact.
__global__ __launch_bounds__(256, 2) void conv3x3(const float* __restrict__ featP,
                                                  const float* __restrict__ wcv,
                                                  const float* __restrict__ rpn_b,
                                                  float* __restrict__ xd) {
    __shared__ float sW[8192];                 // [ic][32 oc] for current tap
    const int band = blockIdx.x & 7;           // tile row (XCD-pinned)
    const int slot = blockIdx.x >> 3;          // 0..63
    const int tx = slot & 7, ocb = slot >> 3;  // tile col, oc-block(32)
    const int oc0 = ocb * 32;
    const int tid = threadIdx.x;
    const int wid = tid >> 6;                  // wave 0..3 -> 8 oc each
    const int lane = tid & 63;
    const int py = lane >> 2, px0 = (lane & 3) * 4;   // wave covers 16x16 px
    const int gy = band * 16 + py, gx0 = tx * 16 + px0;
    const int ocB = oc0 + wid * 8;
    float acc[4][8];
#pragma unroll
    for (int p = 0; p < 4; ++p)
#pragma unroll
        for (int o = 0; o < 8; ++o) acc[p][o] = 0.f;
#pragma unroll
    for (int tap = 0; tap < 9; ++tap) {        // k-major: tap (ky,kx)
        __syncthreads();
        for (int idx = tid; idx < 8192; idx += 256)
            sW[idx] = wcv[tap * 65536 + (idx >> 5) * 256 + oc0 + (idx & 31)];
        __syncthreads();
        const float* fp = featP + (size_t)(gy + tap / 3) * 132 + (gx0 + tap % 3);
        const float* wl = sW + wid * 8;        // wave-uniform -> LDS broadcast
#pragma unroll 4
        for (int ic = 0; ic < 256; ++ic) {     // k-minor: ic ascending
            float4a fA = *(const float4a*)(fp + (size_t)ic * 17160);
            float4a w0 = *(const float4a*)(wl + ic * 32);
            float4a w1 = *(const float4a*)(wl + ic * 32 + 4);
#pragma unroll
            for (int p = 0; p < 4; ++p) {
#pragma unroll
                for (int o = 0; o < 4; ++o)
                    acc[p][o] = __fmaf_rn(fA[p], w0[o], acc[p][o]);
#pragma unroll
                for (int o = 0; o < 4; ++o)
                    acc[p][4 + o] = __fmaf_rn(fA[p], w1[o], acc[p][4 + o]);
            }
        }
    }
#pragma unroll
    for (int p = 0; p < 4; ++p) {
        float* op = xd + (size_t)(gy * 128 + gx0 + p) * 256 + ocB;
#pragma unroll
        for (int o = 0; o < 8; ++o) {
            float v = __fadd_rn(acc[p][o], rpn_b[ocB + o]);
            op[o] = v > 0.f ? v : 0.f;
        }
    }
}

// ---------------- heads+decode FUSED: 1x1 convs -> softmax -> boxes/keys -----
__global__ __launch_bounds__(256, 1) void heads_decode(const float* __restrict__ xd,
                                                       const float* __restrict__ cls_w,
                                                       const float* __restrict__ box_w,
                                                       const float* __restrict__ cls_b,
                                                       const float* __restrict__ box_b,
                                                       float4* __restrict__ boxes,
                                                       u64* __restrict__ keys) {
    __shared__ float sX[4][260];
    __shared__ float sD[4][54];
    const int tid = threadIdx.x;
    const int pix0 = blockIdx.x * 4;
    for (int idx = tid; idx < 1024; idx += 256)
        sX[idx >> 8][idx & 255] = xd[(size_t)(pix0 + (idx >> 8)) * 256 + (idx & 255)];
    __syncthreads();
    if (tid < 216) {
        const int pl = tid / 54, o = tid % 54;
        const float* wr = (o < 18) ? (cls_w + o * 256) : (box_w + (o - 18) * 256);
        const float4* x4 = (const float4*)&sX[pl][0];
        const float4* w4 = (const float4*)wr;
        float acc = 0.f;
        for (int q = 0; q < 64; ++q) {
            float4 xv = x4[q];
            float4 wv = w4[q];
            acc = __fmaf_rn(xv.x, wv.x, acc);
            acc = __fmaf_rn(xv.y, wv.y, acc);
            acc = __fmaf_rn(xv.z, wv.z, acc);
            acc = __fmaf_rn(xv.w, wv.w, acc);
        }
        sD[pl][o] = acc;
    }
    __syncthreads();
    if (tid >= 36) return;
    const int pl = tid / 9, a = tid % 9;
    const int pix = pix0 + pl;
    const float* dt = sD[pl];
    float d[54];
#pragma unroll
    for (int i = 0; i < 54; ++i)
        d[i] = __fadd_rn(dt[i], (i < 18 ? cls_b[i] : box_b[i - 18]));
    float m = d[0];
#pragma unroll
    for (int i = 1; i < 18; ++i) m = fmaxf(m, d[i]);
    float e[18];
#pragma unroll
    for (int i = 0; i < 18; ++i) e[i] = exp_xla(__fsub_rn(d[i], m));
    float s = e[0];
#pragma unroll
    for (int i = 1; i < 18; ++i) s = __fadd_rn(s, e[i]);
    const int y = pix >> 7, x = pix & 127;
    const float shx = (float)(x * 32), shy = (float)(y * 32);
    const float AW[9] = {368.f, 736.f, 1472.f, 256.f, 512.f, 1024.f, 176.f, 352.f, 704.f};
    const float AH[9] = {192.f, 384.f, 768.f, 256.f, 512.f, 1024.f, 352.f, 704.f, 1408.f};
    float score = e[9 + a] / s;
    float wa = AW[a], ha = AH[a];
    float cxa = __fadd_rn(shx, 7.5f), cya = __fadd_rn(shy, 7.5f);
    float dx = d[18 + 4 * a], dyy = d[19 + 4 * a];
    float dw = d[20 + 4 * a], dh = d[21 + 4 * a];
    float cx = __fadd_rn(__fmul_rn(dx, wa), cxa);
    float cy = __fadd_rn(__fmul_rn(dyy, ha), cya);
    float pw = __fmul_rn(wa, exp_xla(dw));
    float ph = __fmul_rn(ha, exp_xla(dh));
    float hx = __fmul_rn(0.5f, pw), hy = __fmul_rn(0.5f, ph);
    float x1 = fminf(fmaxf(__fsub_rn(cx, hx), 0.f), 4095.f);
    float y1 = fminf(fmaxf(__fsub_rn(cy, hy), 0.f), 4095.f);
    float x2 = fminf(fmaxf(__fadd_rn(cx, hx), 0.f), 4095.f);
    float y2 = fminf(fmaxf(__fadd_rn(cy, hy), 0.f), 4095.f);
    float vw = __fadd_rn(__fsub_rn(x2, x1), 1.0f);
    float vh = __fadd_rn(__fsub_rn(y2, y1), 1.0f);
    bool valid = (vw >= 16.0f) && (vh >= 16.0f);
    int i = pix * 9 + a;
    boxes[i] = make_float4(x1, y1, x2, y2);
    u64 k;
    if (valid) {
        u32 b = __float_as_uint(score);
        k = ((u64)(u32)~(b | 0x80000000u) << 32) | (u32)i;
    } else {
        k = (0xFFFFFFFFULL << 32) | (u32)i;
    }
    keys[i] = k;
}

// ---------------- radix select + compact, SINGLE KERNEL ----------------------
// 4 passes of 8 bits over the score word, then inline compact. Inter-block
// sync per pass: device atomics + threadfence + done-counter spin (64 blocks
// on 256 CUs always co-resident). Every block redundantly scans the
// (atomic-RMW-read, XCD-coherent) histogram -> no cross-pass globals.
__global__ __launch_bounds__(256) void radix_compact(const u64* __restrict__ keys,
                                                     u32* __restrict__ ghist,
                                                     u32* done, u32* count,
                                                     u64* __restrict__ ckey,
                                                     u32* __restrict__ cidx,
                                                     u64* __restrict__ alive0) {
    __shared__ u32 lh[256];
    __shared__ u32 sh[256];
    __shared__ u32 incl[256];
    __shared__ u32 bdig, btgt;
    const int t = threadIdx.x;
    if (blockIdx.x == 0 && t < 128) alive0[t] = 0ULL;   // consumed next kernel
    u64 pref = 0;        // uniform across blocks (identical redundant scans)
    u32 target = 6000;
    for (int pass = 0; pass < 4; ++pass) {
        lh[t] = 0;
        __syncthreads();
        const int shift = 56 - 8 * pass;
        for (int i = blockIdx.x * 256 + t; i < 147456; i += 64 * 256) {
            u64 k = keys[i];
            bool match = (pass == 0) || ((k >> (shift + 8)) == pref);
            if (match) atomicAdd(&lh[(u32)(k >> shift) & 0xFFu], 1u);
        }
        __syncthreads();
        if (lh[t]) atomicAdd(&ghist[pass * 256 + t], lh[t]);
        __threadfence();                   // hist visible before done++
        __syncthreads();
        if (t == 0) {
            atomicAdd(done, 1u);
            const u32 need = 64u * (u32)(pass + 1);
            while (atomicAdd(done, 0u) < need) { }   // spin: all 64 co-resident
        }
        __syncthreads();
        u32 hv = atomicAdd(&ghist[pass * 256 + t], 0u);  // coherent RMW read
        sh[t] = hv;
        incl[t] = hv;
        __syncthreads();
        for (int off = 1; off < 256; off <<= 1) {
            u32 v = (t >= off) ? incl[t - off] : 0u;
            __syncthreads();
            incl[t] += v;
            __syncthreads();
        }
        u32 before = incl[t] - sh[t];
        if (before < target && target <= incl[t]) { bdig = (u32)t; btgt = target - before; }
        __syncthreads();
        pref = (pref << 8) | (u64)bdig;
        target = btgt;
    }
    // pref = exact 32-bit score boundary; compact inline (order-independent:
    // rank_scatter ranks by key value). Slack: 6000 + score-word ties <= 6144.
    for (int i = blockIdx.x * 256 + t; i < 147456; i += 64 * 256) {
        u64 k = keys[i];
        if ((k >> 32) <= pref) {
            u32 pos = atomicAdd(count, 1u);
            if (pos < 6144) { ckey[pos] = k; cidx[pos] = (u32)(k & 0xFFFFFFFFu); }
        }
    }
}

// ---------------- exact rank + gather + FUSED alive bitmask ------------------
__global__ __launch_bounds__(256) void rank_scatter(const u64* __restrict__ ckey,
                                                    const u32* __restrict__ cidx,
                                                    const u32* __restrict__ count,
                                                    const float4* __restrict__ boxes,
                                                    float4* __restrict__ tb,
                                                    u64* __restrict__ alive0) {
    __shared__ u64 LK[6144];
    int N = (int)*count; if (N > 6144) N = 6144;
    for (int i = threadIdx.x; i < N; i += 256) LK[i] = ckey[i];
    __syncthreads();
    int e = blockIdx.x * 256 + threadIdx.x;
    if (e >= N) return;
    u64 myK = LK[e];
    u32 myI = cidx[e];
    int rank = 0;
    for (int c = 0; c < N; ++c) rank += (LK[c] < myK);
    if (rank < 6000) {
        tb[rank] = boxes[myI];
        atomicOr(&alive0[rank >> 6], 1ULL << (rank & 63));
    }
}

// ---------------- suppression bitmask, PAIRED layout -------------------------
// Row j = 128 u64; word w at slot 2*(w&63)+(w>>6): lane l's pair (l, 64+l)
// is 16B contiguous -> nms_seq reads it with ONE ds_read_b128; row = 1024B =
// one gload_lds16 sweep.
__global__ __launch_bounds__(256) void nms_mask(const float4* __restrict__ tb,
                                                u64* __restrict__ mask) {
    int tid = blockIdx.x * 256 + threadIdx.x;
    if (tid >= 6000 * 94) return;
    int j = tid / 94, w = tid % 94;
    float4 bj = tb[j];
    float arJ = __fmul_rn(__fadd_rn(__fsub_rn(bj.z, bj.x), 1.0f),
                          __fadd_rn(__fsub_rn(bj.w, bj.y), 1.0f));
    u64 m = 0;
    int base = w * 64;
#pragma unroll 4
    for (int b = 0; b < 64; ++b) {
        int i = base + b;
        if (i >= 6000) break;
        float4 bi = tb[i];
        float arI = __fmul_rn(__fadd_rn(__fsub_rn(bi.z, bi.x), 1.0f),
                              __fadd_rn(__fsub_rn(bi.w, bi.y), 1.0f));
        float xx1 = fmaxf(bj.x, bi.x), yy1 = fmaxf(bj.y, bi.y);
        float xx2 = fminf(bj.z, bi.z), yy2 = fminf(bj.w, bi.w);
        float ww = fmaxf(__fadd_rn(__fsub_rn(xx2, xx1), 1.0f), 0.0f);
        float hh = fmaxf(__fadd_rn(__fsub_rn(yy2, yy1), 1.0f), 0.0f);
        float inter = __fmul_rn(ww, hh);
        float uni = __fsub_rn(__fadd_rn(arJ, arI), inter);
        float iou = inter / uni;
        if (iou > 0.7f) m |= (1ULL << b);
    }
    mask[(size_t)j * 128 + 2 * (w & 63) + (w >> 6)] = m;
}

// ---------------- sequential NMS v4: paired rows, dbuf prefetched window -----
__global__ __launch_bounds__(64, 1) void nms_seq(const u64* __restrict__ alive0,
                                                 const u64* __restrict__ mask,
                                                 const float4* __restrict__ tb,
                                                 float* __restrict__ out) {
    __shared__ __align__(16) u64 lwin[2][64 * 128];   // 2 x 64KB windows
    __shared__ u32 sel[1000];
    const int lane = threadIdx.x;
    u64 wl = alive0[lane];
    u64 wh = (lane < 30) ? alive0[64 + lane] : 0ULL;
    int base = -1000000;   // force refill on first selection
    int pbase = -1;        // prefetch window start (-1 = none), in buf[cur^1]
    int cur = 0;
    int k = 0;
    for (; k < 1000; ++k) {
        // ---- j = first alive (strictly increasing across iterations) ----
        int j;
        {
            u64 blo = __ballot(wl != 0ULL);
            if (blo) {
                int l = __ffsll((long long)blo) - 1;
                u32 a = __builtin_amdgcn_readlane((u32)wl, l);
                u32 b = __builtin_amdgcn_readlane((u32)(wl >> 32), l);
                u64 w = ((u64)b << 32) | (u64)a;
                j = l * 64 + __ffsll((long long)w) - 1;
            } else {
                u64 bhi = __ballot(wh != 0ULL);
                if (!bhi) break;  // exhausted: remaining out rows stay 0
                int l = __ffsll((long long)bhi) - 1;
                u32 a = __builtin_amdgcn_readlane((u32)wh, l);
                u32 b = __builtin_amdgcn_readlane((u32)(wh >> 32), l);
                u64 w = ((u64)b << 32) | (u64)a;
                j = (64 + l) * 64 + __ffsll((long long)w) - 1;
            }
        }
        if (lane == 0) sel[k] = (u32)j;
        // ---- window management (wave-uniform branch) ----
        if (j >= base + 64) {
            if (pbase >= 0 && j < pbase + 64) {
                // prefetched buffer covers j: just retire outstanding loads
                asm volatile("s_waitcnt vmcnt(0)" ::: "memory");
                cur ^= 1;
                base = pbase;
            } else {
                // jump past prefetch (or first iter): full refill into cur
                int js = (j > 5936) ? 5936 : j;     // clamp: stay inside mask
                asm volatile("s_waitcnt vmcnt(0)" ::: "memory");
                const char* gsrc = (const char*)mask + (size_t)js * 1024 + (size_t)lane * 16;
                char* ldst = (char*)&lwin[cur][0];
#pragma unroll
                for (int i = 0; i < 64; ++i)
                    gload_lds16(gsrc + (size_t)i * 1024, ldst + i * 1024);
                base = js;
                asm volatile("s_waitcnt vmcnt(0)" ::: "memory");
            }
            pbase = -1;
            if (base + 64 < 6000) {
                // issue prefetch of next window into the other buffer (NO wait)
                int ps = (base + 64 > 5936) ? 5936 : (base + 64);  // clamp
                const char* gs2 = (const char*)mask + (size_t)ps * 1024 + (size_t)lane * 16;
                char* ld2 = (char*)&lwin[cur ^ 1][0];
#pragma unroll
                for (int i = 0; i < 64; ++i)
                    gload_lds16(gs2 + (size_t)i * 1024, ld2 + i * 1024);
                pbase = ps;
            }
        }
        const int s = j - base;
        u64x2 rd = *(const u64x2*)&lwin[cur][(size_t)s * 128 + 2 * lane];
        u64 rl = rd.x;
        u64 rh = rd.y;
        // ---- apply row j (kills j itself via iou==1) ----
        wl &= ~rl;
        if (lane < 30) wh &= ~rh;
    }
    // ---- bulk gather: rois[k] = (0, tb[sel[k]]) — off the serial path ----
    __syncthreads();
    for (int r = lane; r < k; r += 64) {
        int j = (int)sel[r];
        float4 bj = tb[j];
        out[r * 5 + 1] = bj.x;
        out[r * 5 + 2] = bj.y;
        out[r * 5 + 3] = bj.z;
        out[r * 5 + 4] = bj.w;
    }
}

// ---------------- host ----------------
extern "C" void kernel_launch(void* const* d_in, const int* in_sizes, int n_in,
                              void* d_out, int out_size, void* d_ws, size_t ws_size,
                              hipStream_t stream) {
    const float *feat = nullptr, *rpn_w = nullptr, *rpn_b = nullptr;
    const float *cls_w = nullptr, *cls_b = nullptr, *box_w = nullptr, *box_b = nullptr;
    for (int i = 0; i < n_in; ++i) {
        switch (in_sizes[i]) {
            case 4194304: feat  = (const float*)d_in[i]; break;
            case 589824:  rpn_w = (const float*)d_in[i]; break;
            case 256:     rpn_b = (const float*)d_in[i]; break;
            case 4608:    cls_w = (const float*)d_in[i]; break;
            case 18:      cls_b = (const float*)d_in[i]; break;
            case 9216:    box_w = (const float*)d_in[i]; break;
            case 36:      box_b = (const float*)d_in[i]; break;
            default: break;  // image dims hardcoded (4096)
        }
    }

    char* w = (char*)d_ws;
    u32* ctlCount  = (u32*)(w + OFF_CTL + 12);
    u32* done      = (u32*)(w + OFF_CTL + 16);
    u32* hist      = (u32*)(w + OFF_HIST);
    float* wcv     = (float*)(w + OFF_WCV);
    float* xd      = (float*)(w + OFF_XD);
    float4* boxes  = (float4*)(w + OFF_BOX);
    u64* keys      = (u64*)(w + OFF_KEYS);
    u64* ckey      = (u64*)(w + OFF_CKEY);
    u32* cidx      = (u32*)(w + OFF_CIDX);
    float4* tb     = (float4*)(w + OFF_TB);
    u64* alive0    = (u64*)(w + OFF_ALIVE);
    u64* maskP     = (u64*)(w + OFF_MASKP);      // aliases featP (dead by then)
    float* featP   = (float*)(w + OFF_FPAD);

    hipMemsetAsync(d_ws, 0, OFF_HIST + 8 * 256 * 4, stream);  // ctl + done + hists
    hipMemsetAsync(d_out, 0, (size_t)out_size * sizeof(float), stream);

    prep_all<<<2304 + 17160, 256, 0, stream>>>(rpn_w, wcv, feat, featP);
    conv3x3<<<512, 256, 0, stream>>>(featP, wcv, rpn_b, xd);
    heads_decode<<<4096, 256, 0, stream>>>(xd, cls_w, box_w, cls_b, box_b, boxes, keys);
    radix_compact<<<64, 256, 0, stream>>>(keys, hist, done, ctlCount, ckey, cidx, alive0);
    rank_scatter<<<24, 256, 0, stream>>>(ckey, cidx, ctlCount, boxes, tb, alive0);
    nms_mask<<<2204, 256, 0, stream>>>(tb, maskP);
    nms_seq<<<1, 64, 0, stream>>>(alive0, maskP, tb, (float*)d_out);
}